// Round 1
// baseline (7474.229 us; speedup 1.0000x reference)
//
#include <hip/hip_runtime.h>

#define NB_V 65536
#define TOPK 4096
#define FPSK 2048

// ---------------------------------------------------------------------------
// GEMM: H(N,256) = A(N,256) @ W(256,256), accumulator precision templated.
// ACC=double for the cls branch (discrete top-k selection downstream needs
// near-exact scores); ACC=float for the offset branch (2% tolerance).
// ---------------------------------------------------------------------------
template <typename ACC>
__global__ __launch_bounds__(256) void k_gemm(const float* __restrict__ A,
                                              const float* __restrict__ W,
                                              float* __restrict__ H, int N) {
  __shared__ float As[64][36];  // 64 rows x 32 k, padded
  __shared__ float Bs[32][68];  // 32 k x 64 cols, padded
  const int tid = threadIdx.x;
  const int tx = tid & 15, ty = tid >> 4;
  const int cb = blockIdx.x & 3;
  const int rb = blockIdx.x >> 2;
  ACC acc[4][4];
#pragma unroll
  for (int i = 0; i < 4; ++i)
#pragma unroll
    for (int j = 0; j < 4; ++j) acc[i][j] = (ACC)0;

  for (int kc = 0; kc < 256; kc += 32) {
#pragma unroll
    for (int l = 0; l < 2; ++l) {
      int f = tid + 256 * l;
      int r = f >> 3, qc = (f & 7) * 4;
      float4 v = *reinterpret_cast<const float4*>(&A[(size_t)(rb * 64 + r) * 256 + kc + qc]);
      *reinterpret_cast<float4*>(&As[r][qc]) = v;
    }
#pragma unroll
    for (int l = 0; l < 2; ++l) {
      int f = tid + 256 * l;
      int kr = f >> 4, qc = (f & 15) * 4;
      float4 v = *reinterpret_cast<const float4*>(&W[(size_t)(kc + kr) * 256 + cb * 64 + qc]);
      *reinterpret_cast<float4*>(&Bs[kr][qc]) = v;
    }
    __syncthreads();
#pragma unroll 4
    for (int kk = 0; kk < 32; ++kk) {
      float a0[4], b0[4];
#pragma unroll
      for (int i = 0; i < 4; ++i) a0[i] = As[ty + 16 * i][kk];
#pragma unroll
      for (int j = 0; j < 4; ++j) b0[j] = Bs[kk][tx + 16 * j];
#pragma unroll
      for (int i = 0; i < 4; ++i)
#pragma unroll
        for (int j = 0; j < 4; ++j) acc[i][j] += (ACC)a0[i] * (ACC)b0[j];
    }
    __syncthreads();
  }
#pragma unroll
  for (int i = 0; i < 4; ++i)
#pragma unroll
    for (int j = 0; j < 4; ++j)
      H[(size_t)(rb * 64 + ty + 16 * i) * 256 + cb * 64 + tx + 16 * j] = (float)acc[i][j];
}

// ---------------------------------------------------------------------------
// Column mean/meansq partials (f64, deterministic fixed reduction tree).
// 1024 blocks, each handles N/1024 rows; thread t = column t of both H's.
// ---------------------------------------------------------------------------
__global__ __launch_bounds__(256) void k_stats(const float* __restrict__ Hoff,
                                               const float* __restrict__ Hcls,
                                               double* __restrict__ part, int N) {
  const int rpb = N / 1024;
  const int r0 = blockIdx.x * rpb;
  const int t = threadIdx.x;
  double s0 = 0, q0 = 0, s1 = 0, q1 = 0;
  for (int r = r0; r < r0 + rpb; ++r) {
    double v = (double)Hoff[(size_t)r * 256 + t];
    s0 += v; q0 = fma(v, v, q0);
    double w = (double)Hcls[(size_t)r * 256 + t];
    s1 += w; q1 = fma(w, w, q1);
  }
  double* o = part + ((size_t)blockIdx.x * 512 + t) * 2;
  o[0] = s0; o[1] = q0;
  o = part + ((size_t)blockIdx.x * 512 + 256 + t) * 2;
  o[0] = s1; o[1] = q1;
}

__global__ void k_statsfin(const double* __restrict__ part,
                           const float* __restrict__ g_off, const float* __restrict__ be_off,
                           const float* __restrict__ g_cls, const float* __restrict__ be_cls,
                           double* __restrict__ aarr, double* __restrict__ carr,
                           int nparts, int N) {
  const int c = threadIdx.x;  // 512 threads
  double s = 0, q = 0;
  for (int p = 0; p < nparts; ++p) {
    s += part[((size_t)p * 512 + c) * 2];
    q += part[((size_t)p * 512 + c) * 2 + 1];
  }
  double mean = s / (double)N;
  double var = q / (double)N - mean * mean;
  double g = (c < 256) ? (double)g_off[c] : (double)g_cls[c - 256];
  double be = (c < 256) ? (double)be_off[c] : (double)be_cls[c - 256];
  double a = g / sqrt(var + 1e-5);
  aarr[c] = a;
  carr[c] = be - mean * a;  // val = h*a + c  ==  (h-mean)*rsqrt*gamma + beta
}

// ---------------------------------------------------------------------------
// Fused BN+ReLU+layer2 for both branches; writes seeds, seed_cls, votes, and
// the f64-score sort key. One wave per row; lane l handles cols {l+64q}.
// ---------------------------------------------------------------------------
__global__ __launch_bounds__(256) void k_fuse(const float* __restrict__ Hoff,
                                              const float* __restrict__ Hcls,
                                              const float* __restrict__ xyz,
                                              const float* __restrict__ w_off2,
                                              const float* __restrict__ b_off2,
                                              const float* __restrict__ w_cls2,
                                              const float* __restrict__ b_cls2,
                                              const double* __restrict__ aarr,
                                              const double* __restrict__ carr,
                                              float* __restrict__ out_seeds,
                                              float* __restrict__ out_cls,
                                              float* __restrict__ out_votes,
                                              unsigned long long* __restrict__ keys,
                                              int N) {
  __shared__ double sa[512], sc[512];
  __shared__ double w2[512][3];
  const int tid = threadIdx.x;
  for (int i = tid; i < 512; i += 256) {
    sa[i] = aarr[i];
    sc[i] = carr[i];
#pragma unroll
    for (int k = 0; k < 3; ++k)
      w2[i][k] = (i < 256) ? (double)w_off2[i * 3 + k] : (double)w_cls2[(i - 256) * 3 + k];
  }
  __syncthreads();
  const int lane = tid & 63, wid = tid >> 6;
  const int gw = blockIdx.x * 4 + wid;  // 4096 waves total
  for (int r = gw; r < N; r += 4096) {
    double po0 = 0, po1 = 0, po2 = 0, pc0 = 0, pc1 = 0, pc2 = 0;
#pragma unroll
    for (int q = 0; q < 4; ++q) {
      int c = lane + 64 * q;
      double h = (double)Hoff[(size_t)r * 256 + c];
      double v = fma(h, sa[c], sc[c]);
      v = v > 0.0 ? v : 0.0;
      po0 = fma(v, w2[c][0], po0);
      po1 = fma(v, w2[c][1], po1);
      po2 = fma(v, w2[c][2], po2);
      int c2 = 256 + c;
      double h2 = (double)Hcls[(size_t)r * 256 + c];
      double v2 = fma(h2, sa[c2], sc[c2]);
      v2 = v2 > 0.0 ? v2 : 0.0;
      pc0 = fma(v2, w2[c2][0], pc0);
      pc1 = fma(v2, w2[c2][1], pc1);
      pc2 = fma(v2, w2[c2][2], pc2);
    }
#pragma unroll
    for (int off = 32; off; off >>= 1) {
      po0 += __shfl_xor(po0, off); po1 += __shfl_xor(po1, off); po2 += __shfl_xor(po2, off);
      pc0 += __shfl_xor(pc0, off); pc1 += __shfl_xor(pc1, off); pc2 += __shfl_xor(pc2, off);
    }
    if (lane == 0) {
      float x = xyz[(size_t)r * 3], y = xyz[(size_t)r * 3 + 1], z = xyz[(size_t)r * 3 + 2];
      float bs = (float)(r >> 16);
      out_seeds[(size_t)r * 4 + 0] = bs;
      out_seeds[(size_t)r * 4 + 1] = x;
      out_seeds[(size_t)r * 4 + 2] = y;
      out_seeds[(size_t)r * 4 + 3] = z;
      double offv[3] = {po0 + (double)b_off2[0], po1 + (double)b_off2[1], po2 + (double)b_off2[2]};
      const double rng[3] = {3.0, 3.0, 2.0};
      float pxyz[3] = {x, y, z};
      out_votes[(size_t)r * 4 + 0] = bs;
#pragma unroll
      for (int k = 0; k < 3; ++k) {
        double lim = offv[k];
        lim = lim < -rng[k] ? -rng[k] : lim;
        lim = lim > rng[k] ? rng[k] : lim;
        out_votes[(size_t)r * 4 + 1 + k] = (float)((double)pxyz[k] + lim);
      }
      double c0 = pc0 + (double)b_cls2[0];
      double c1 = pc1 + (double)b_cls2[1];
      double c2v = pc2 + (double)b_cls2[2];
      out_cls[(size_t)r * 3 + 0] = (float)c0;
      out_cls[(size_t)r * 3 + 1] = (float)c1;
      out_cls[(size_t)r * 3 + 2] = (float)c2v;
      double s = c0 > c1 ? c0 : c1;
      s = s > c2v ? s : c2v;
      long long bits = __double_as_longlong(s);
      unsigned long long key =
          bits >= 0 ? ((unsigned long long)bits | 0x8000000000000000ull) : ~((unsigned long long)bits);
      keys[r] = key;
    }
  }
}

// ---------------------------------------------------------------------------
// Per-batch top-4096: 8-pass radix select on u64 keys, gather, then LDS
// bitonic sort by (key desc, idx asc) — exactly lax.top_k's order/tie rule.
// ---------------------------------------------------------------------------
__global__ __launch_bounds__(1024) void k_topk(const unsigned long long* __restrict__ keys,
                                               unsigned int* __restrict__ topk) {
  const int b = blockIdx.x;
  const unsigned long long* K = keys + (size_t)b * NB_V;
  __shared__ unsigned int hist[256];
  __shared__ unsigned long long pfx_s;
  __shared__ int want_s;
  __shared__ unsigned long long skey[TOPK];
  __shared__ unsigned int sidx[TOPK];
  __shared__ int cnt_hi, cnt_eq;
  __shared__ unsigned int eq_idx[1024];
  const int tid = threadIdx.x;
  if (tid == 0) { pfx_s = 0ull; want_s = TOPK; }
  __syncthreads();
  for (int p = 0; p < 8; ++p) {
    const int shift = 56 - 8 * p;
    if (tid < 256) hist[tid] = 0;
    __syncthreads();
    unsigned long long pfx = pfx_s;
    for (int i = tid; i < NB_V; i += 1024) {
      unsigned long long k = K[i];
      bool ok;
      if (p == 0) ok = true;
      else ok = ((k >> (shift + 8)) == (pfx >> (shift + 8)));
      if (ok) atomicAdd(&hist[(unsigned)(k >> shift) & 255u], 1u);
    }
    __syncthreads();
    if (tid == 0) {
      int want = want_s;
      int cum = 0, d = 255;
      for (; d >= 0; --d) {
        int c = (int)hist[d];
        if (cum + c >= want) break;
        cum += c;
      }
      want_s = want - cum;
      pfx_s = pfx_s | ((unsigned long long)d << shift);
    }
    __syncthreads();
  }
  const unsigned long long Kthr = pfx_s;
  const int T = want_s;
  if (tid == 0) { cnt_hi = 0; cnt_eq = 0; }
  __syncthreads();
  for (int i = tid; i < NB_V; i += 1024) {
    unsigned long long k = K[i];
    if (k > Kthr) {
      int pos = atomicAdd(&cnt_hi, 1);
      skey[pos] = k;
      sidx[pos] = (unsigned)i;
    } else if (k == Kthr) {
      int pos = atomicAdd(&cnt_eq, 1);
      if (pos < 1024) eq_idx[pos] = (unsigned)i;
    }
  }
  __syncthreads();
  if (tid == 0) {
    int m = cnt_eq; if (m > 1024) m = 1024;
    for (int a2 = 1; a2 < m; ++a2) {  // insertion sort (m is tiny)
      unsigned v = eq_idx[a2];
      int b2 = a2 - 1;
      while (b2 >= 0 && eq_idx[b2] > v) { eq_idx[b2 + 1] = eq_idx[b2]; --b2; }
      eq_idx[b2 + 1] = v;
    }
    for (int t = 0; t < T; ++t) { skey[cnt_hi + t] = Kthr; sidx[cnt_hi + t] = eq_idx[t]; }
  }
  __syncthreads();
  // bitonic sort: final order = key desc, idx asc
  for (int k2 = 2; k2 <= TOPK; k2 <<= 1) {
    for (int j = k2 >> 1; j > 0; j >>= 1) {
      for (int i = tid; i < TOPK; i += 1024) {
        int ix = i ^ j;
        if (ix > i) {
          unsigned long long ka = skey[i], kb = skey[ix];
          unsigned int ia = sidx[i], ib = sidx[ix];
          bool a_first = (ka > kb) || (ka == kb && ia < ib);
          bool up = (i & k2) == 0;
          if (up ? !a_first : a_first) {
            skey[i] = kb; skey[ix] = ka;
            sidx[i] = ib; sidx[ix] = ia;
          }
        }
      }
      __syncthreads();
    }
  }
  for (int i = tid; i < TOPK; i += 1024) topk[(size_t)b * TOPK + i] = sidx[i];
}

// ---------------------------------------------------------------------------
// D-FPS: one block per batch, 1024 threads x 4 points in registers.
// Distances in f64 (non-contracted) to match the np/f64 ground truth;
// argmax = first occurrence (strict >, tie -> smaller position).
// ---------------------------------------------------------------------------
__global__ __launch_bounds__(1024) void k_fps(const float* __restrict__ xyz,
                                              const unsigned int* __restrict__ topk,
                                              unsigned int* __restrict__ fpspos) {
  const int b = blockIdx.x;
  const int tid = threadIdx.x;
  __shared__ float ls[3];
  __shared__ double wval[16];
  __shared__ int wpos[16];
  float px[4], py[4], pz[4];
  double dist[4];
#pragma unroll
  for (int j = 0; j < 4; ++j) {
    int p = tid * 4 + j;
    unsigned idx = topk[(size_t)b * TOPK + p];
    size_t base = ((size_t)b * NB_V + idx) * 3;
    px[j] = xyz[base]; py[j] = xyz[base + 1]; pz[j] = xyz[base + 2];
    dist[j] = 1e10;
  }
  if (tid == 0) {
    ls[0] = px[0]; ls[1] = py[0]; ls[2] = pz[0];
    fpspos[(size_t)b * FPSK] = 0u;
  }
  __syncthreads();
  const int lane = tid & 63;
  const int wid = tid >> 6;
  for (int it = 1; it < FPSK; ++it) {
    double lx = (double)ls[0], ly = (double)ls[1], lz = (double)ls[2];
    double bv = -1.0;
    int bp = 1 << 30;
#pragma unroll
    for (int j = 0; j < 4; ++j) {
      double dx = (double)px[j] - lx;
      double dy = (double)py[j] - ly;
      double dz = (double)pz[j] - lz;
      double d = __dadd_rn(__dadd_rn(__dmul_rn(dx, dx), __dmul_rn(dy, dy)), __dmul_rn(dz, dz));
      if (d < dist[j]) dist[j] = d;
      if (dist[j] > bv) { bv = dist[j]; bp = tid * 4 + j; }
    }
#pragma unroll
    for (int off = 32; off; off >>= 1) {
      double ov = __shfl_xor(bv, off);
      int op = __shfl_xor(bp, off);
      if (ov > bv || (ov == bv && op < bp)) { bv = ov; bp = op; }
    }
    if (lane == 0) { wval[wid] = bv; wpos[wid] = bp; }
    __syncthreads();
    double wv = wval[0];
    int wp = wpos[0];
#pragma unroll
    for (int w = 1; w < 16; ++w) {
      double v = wval[w]; int p2 = wpos[w];
      if (v > wv || (v == wv && p2 < wp)) { wv = v; wp = p2; }
    }
    if (tid == (wp >> 2)) {
      int j = wp & 3;
      ls[0] = px[j]; ls[1] = py[j]; ls[2] = pz[j];
    }
    if (tid == 0) fpspos[(size_t)b * FPSK + it] = (unsigned)wp;
    __syncthreads();
  }
}

// ---------------------------------------------------------------------------
// Final gather: fps_indices (as float), vote_candidates, vote_features.
// ---------------------------------------------------------------------------
__global__ __launch_bounds__(256) void k_gather(const unsigned int* __restrict__ topk,
                                                const unsigned int* __restrict__ fpspos,
                                                const float* __restrict__ feats,
                                                const float* __restrict__ votes_out,
                                                float* __restrict__ o0, float* __restrict__ o1,
                                                float* __restrict__ o5) {
  const int r = blockIdx.x;  // 0 .. B*FPSK-1
  const int b = r / FPSK;
  __shared__ unsigned int gsh;
  if (threadIdx.x == 0) {
    unsigned pos = fpspos[r];
    unsigned local = topk[(size_t)b * TOPK + pos];
    gsh = (unsigned)(b * NB_V) + local;
  }
  __syncthreads();
  const unsigned g = gsh;
  o1[(size_t)r * 256 + threadIdx.x] = feats[(size_t)g * 256 + threadIdx.x];
  if (threadIdx.x < 4) o0[(size_t)r * 4 + threadIdx.x] = votes_out[(size_t)g * 4 + threadIdx.x];
  if (threadIdx.x == 4) o5[r] = (float)g;
}

// ---------------------------------------------------------------------------
extern "C" void kernel_launch(void* const* d_in, const int* in_sizes, int n_in,
                              void* d_out, int out_size, void* d_ws, size_t ws_size,
                              hipStream_t stream) {
  const float* xyz = (const float*)d_in[0];
  const float* feats = (const float*)d_in[1];
  const float* w_off1 = (const float*)d_in[2];
  const float* g_off1 = (const float*)d_in[3];
  const float* be_off1 = (const float*)d_in[4];
  const float* w_off2 = (const float*)d_in[5];
  const float* b_off2 = (const float*)d_in[6];
  const float* w_cls1 = (const float*)d_in[7];
  const float* g_cls1 = (const float*)d_in[8];
  const float* be_cls1 = (const float*)d_in[9];
  const float* w_cls2 = (const float*)d_in[10];
  const float* b_cls2 = (const float*)d_in[11];

  const int N = in_sizes[0] / 3;
  const int B = N / NB_V;
  const int BP = B * FPSK;

  float* out = (float*)d_out;
  float* o0 = out;                           // vote_candidates (BP,4)
  float* o1 = o0 + (size_t)BP * 4;           // vote_features   (BP,256)
  float* o2 = o1 + (size_t)BP * 256;         // seeds           (N,4)
  float* o3 = o2 + (size_t)N * 4;            // seed_cls        (N,3)
  float* o4 = o3 + (size_t)N * 3;            // votes           (N,4)
  float* o5 = o4 + (size_t)N * 4;            // fps_indices     (BP,)

  char* w = (char*)d_ws;
  float* Hoff = (float*)w;                                       // N*256*4
  float* Hcls = (float*)(w + (size_t)N * 1024);                  // N*256*4
  double* part = (double*)(w + (size_t)N * 2048);                // 1024*512*2*8
  double* aarr = (double*)(w + (size_t)N * 2048 + 8388608);      // 512*8
  double* carr = aarr + 512;                                     // 512*8
  unsigned long long* keys =
      (unsigned long long*)(w + (size_t)N * 2048 + 8388608 + 8192);       // N*8
  unsigned int* topkbuf = (unsigned int*)((char*)keys + (size_t)N * 8);   // B*4096*4
  unsigned int* fpspos = topkbuf + (size_t)B * TOPK;                      // B*2048*4

  k_gemm<float><<<dim3((N / 64) * 4), dim3(256), 0, stream>>>(feats, w_off1, Hoff, N);
  k_gemm<double><<<dim3((N / 64) * 4), dim3(256), 0, stream>>>(feats, w_cls1, Hcls, N);
  k_stats<<<dim3(1024), dim3(256), 0, stream>>>(Hoff, Hcls, part, N);
  k_statsfin<<<dim3(1), dim3(512), 0, stream>>>(part, g_off1, be_off1, g_cls1, be_cls1,
                                                aarr, carr, 1024, N);
  k_fuse<<<dim3(1024), dim3(256), 0, stream>>>(Hoff, Hcls, xyz, w_off2, b_off2, w_cls2,
                                               b_cls2, aarr, carr, o2, o3, o4, keys, N);
  k_topk<<<dim3(B), dim3(1024), 0, stream>>>(keys, topkbuf);
  k_fps<<<dim3(B), dim3(1024), 0, stream>>>(xyz, topkbuf, fpspos);
  k_gather<<<dim3(BP), dim3(256), 0, stream>>>(topkbuf, fpspos, feats, o4, o0, o1, o5);
}

// Round 2
// 7290.540 us; speedup vs baseline: 1.0252x; 1.0252x over previous
//
#include <hip/hip_runtime.h>

#define NB_V 65536
#define TOPK 4096
#define FPSK 2048

// ---------------------------------------------------------------------------
// GEMM: H(N,256) = A(N,256) @ W(256,256), accumulator precision templated.
// ACC=double for the cls branch (discrete top-k selection downstream needs
// near-exact scores); ACC=float for the offset branch (2% tolerance).
// ---------------------------------------------------------------------------
template <typename ACC>
__global__ __launch_bounds__(256) void k_gemm(const float* __restrict__ A,
                                              const float* __restrict__ W,
                                              float* __restrict__ H, int N) {
  __shared__ float As[64][36];  // 64 rows x 32 k, padded
  __shared__ float Bs[32][68];  // 32 k x 64 cols, padded
  const int tid = threadIdx.x;
  const int tx = tid & 15, ty = tid >> 4;
  const int cb = blockIdx.x & 3;
  const int rb = blockIdx.x >> 2;
  ACC acc[4][4];
#pragma unroll
  for (int i = 0; i < 4; ++i)
#pragma unroll
    for (int j = 0; j < 4; ++j) acc[i][j] = (ACC)0;

  for (int kc = 0; kc < 256; kc += 32) {
#pragma unroll
    for (int l = 0; l < 2; ++l) {
      int f = tid + 256 * l;
      int r = f >> 3, qc = (f & 7) * 4;
      float4 v = *reinterpret_cast<const float4*>(&A[(size_t)(rb * 64 + r) * 256 + kc + qc]);
      *reinterpret_cast<float4*>(&As[r][qc]) = v;
    }
#pragma unroll
    for (int l = 0; l < 2; ++l) {
      int f = tid + 256 * l;
      int kr = f >> 4, qc = (f & 15) * 4;
      float4 v = *reinterpret_cast<const float4*>(&W[(size_t)(kc + kr) * 256 + cb * 64 + qc]);
      *reinterpret_cast<float4*>(&Bs[kr][qc]) = v;
    }
    __syncthreads();
#pragma unroll 4
    for (int kk = 0; kk < 32; ++kk) {
      float a0[4], b0[4];
#pragma unroll
      for (int i = 0; i < 4; ++i) a0[i] = As[ty + 16 * i][kk];
#pragma unroll
      for (int j = 0; j < 4; ++j) b0[j] = Bs[kk][tx + 16 * j];
#pragma unroll
      for (int i = 0; i < 4; ++i)
#pragma unroll
        for (int j = 0; j < 4; ++j) acc[i][j] += (ACC)a0[i] * (ACC)b0[j];
    }
    __syncthreads();
  }
#pragma unroll
  for (int i = 0; i < 4; ++i)
#pragma unroll
    for (int j = 0; j < 4; ++j)
      H[(size_t)(rb * 64 + ty + 16 * i) * 256 + cb * 64 + tx + 16 * j] = (float)acc[i][j];
}

// ---------------------------------------------------------------------------
// Column mean/meansq partials (f64, deterministic fixed reduction tree).
// ---------------------------------------------------------------------------
__global__ __launch_bounds__(256) void k_stats(const float* __restrict__ Hoff,
                                               const float* __restrict__ Hcls,
                                               double* __restrict__ part, int N) {
  const int rpb = N / 1024;
  const int r0 = blockIdx.x * rpb;
  const int t = threadIdx.x;
  double s0 = 0, q0 = 0, s1 = 0, q1 = 0;
  for (int r = r0; r < r0 + rpb; ++r) {
    double v = (double)Hoff[(size_t)r * 256 + t];
    s0 += v; q0 = fma(v, v, q0);
    double w = (double)Hcls[(size_t)r * 256 + t];
    s1 += w; q1 = fma(w, w, q1);
  }
  double* o = part + ((size_t)blockIdx.x * 512 + t) * 2;
  o[0] = s0; o[1] = q0;
  o = part + ((size_t)blockIdx.x * 512 + 256 + t) * 2;
  o[0] = s1; o[1] = q1;
}

__global__ void k_statsfin(const double* __restrict__ part,
                           const float* __restrict__ g_off, const float* __restrict__ be_off,
                           const float* __restrict__ g_cls, const float* __restrict__ be_cls,
                           double* __restrict__ aarr, double* __restrict__ carr,
                           int nparts, int N) {
  const int c = threadIdx.x;  // 512 threads
  double s = 0, q = 0;
  for (int p = 0; p < nparts; ++p) {
    s += part[((size_t)p * 512 + c) * 2];
    q += part[((size_t)p * 512 + c) * 2 + 1];
  }
  double mean = s / (double)N;
  double var = q / (double)N - mean * mean;
  double g = (c < 256) ? (double)g_off[c] : (double)g_cls[c - 256];
  double be = (c < 256) ? (double)be_off[c] : (double)be_cls[c - 256];
  double a = g / sqrt(var + 1e-5);
  aarr[c] = a;
  carr[c] = be - mean * a;  // val = h*a + c  ==  (h-mean)*rsqrt*gamma + beta
}

// ---------------------------------------------------------------------------
// Fused BN+ReLU+layer2 for both branches; writes seeds, seed_cls, votes, and
// the f64-score sort key. One wave per row; lane l handles cols {l+64q}.
// ---------------------------------------------------------------------------
__global__ __launch_bounds__(256) void k_fuse(const float* __restrict__ Hoff,
                                              const float* __restrict__ Hcls,
                                              const float* __restrict__ xyz,
                                              const float* __restrict__ w_off2,
                                              const float* __restrict__ b_off2,
                                              const float* __restrict__ w_cls2,
                                              const float* __restrict__ b_cls2,
                                              const double* __restrict__ aarr,
                                              const double* __restrict__ carr,
                                              float* __restrict__ out_seeds,
                                              float* __restrict__ out_cls,
                                              float* __restrict__ out_votes,
                                              unsigned long long* __restrict__ keys,
                                              int N) {
  __shared__ double sa[512], sc[512];
  __shared__ double w2[512][3];
  const int tid = threadIdx.x;
  for (int i = tid; i < 512; i += 256) {
    sa[i] = aarr[i];
    sc[i] = carr[i];
#pragma unroll
    for (int k = 0; k < 3; ++k)
      w2[i][k] = (i < 256) ? (double)w_off2[i * 3 + k] : (double)w_cls2[(i - 256) * 3 + k];
  }
  __syncthreads();
  const int lane = tid & 63, wid = tid >> 6;
  const int gw = blockIdx.x * 4 + wid;  // 4096 waves total
  for (int r = gw; r < N; r += 4096) {
    double po0 = 0, po1 = 0, po2 = 0, pc0 = 0, pc1 = 0, pc2 = 0;
#pragma unroll
    for (int q = 0; q < 4; ++q) {
      int c = lane + 64 * q;
      double h = (double)Hoff[(size_t)r * 256 + c];
      double v = fma(h, sa[c], sc[c]);
      v = v > 0.0 ? v : 0.0;
      po0 = fma(v, w2[c][0], po0);
      po1 = fma(v, w2[c][1], po1);
      po2 = fma(v, w2[c][2], po2);
      int c2 = 256 + c;
      double h2 = (double)Hcls[(size_t)r * 256 + c];
      double v2 = fma(h2, sa[c2], sc[c2]);
      v2 = v2 > 0.0 ? v2 : 0.0;
      pc0 = fma(v2, w2[c2][0], pc0);
      pc1 = fma(v2, w2[c2][1], pc1);
      pc2 = fma(v2, w2[c2][2], pc2);
    }
#pragma unroll
    for (int off = 32; off; off >>= 1) {
      po0 += __shfl_xor(po0, off); po1 += __shfl_xor(po1, off); po2 += __shfl_xor(po2, off);
      pc0 += __shfl_xor(pc0, off); pc1 += __shfl_xor(pc1, off); pc2 += __shfl_xor(pc2, off);
    }
    if (lane == 0) {
      float x = xyz[(size_t)r * 3], y = xyz[(size_t)r * 3 + 1], z = xyz[(size_t)r * 3 + 2];
      float bs = (float)(r >> 16);
      out_seeds[(size_t)r * 4 + 0] = bs;
      out_seeds[(size_t)r * 4 + 1] = x;
      out_seeds[(size_t)r * 4 + 2] = y;
      out_seeds[(size_t)r * 4 + 3] = z;
      double offv[3] = {po0 + (double)b_off2[0], po1 + (double)b_off2[1], po2 + (double)b_off2[2]};
      const double rng[3] = {3.0, 3.0, 2.0};
      float pxyz[3] = {x, y, z};
      out_votes[(size_t)r * 4 + 0] = bs;
#pragma unroll
      for (int k = 0; k < 3; ++k) {
        double lim = offv[k];
        lim = lim < -rng[k] ? -rng[k] : lim;
        lim = lim > rng[k] ? rng[k] : lim;
        out_votes[(size_t)r * 4 + 1 + k] = (float)((double)pxyz[k] + lim);
      }
      double c0 = pc0 + (double)b_cls2[0];
      double c1 = pc1 + (double)b_cls2[1];
      double c2v = pc2 + (double)b_cls2[2];
      out_cls[(size_t)r * 3 + 0] = (float)c0;
      out_cls[(size_t)r * 3 + 1] = (float)c1;
      out_cls[(size_t)r * 3 + 2] = (float)c2v;
      double s = c0 > c1 ? c0 : c1;
      s = s > c2v ? s : c2v;
      long long bits = __double_as_longlong(s);
      unsigned long long key =
          bits >= 0 ? ((unsigned long long)bits | 0x8000000000000000ull) : ~((unsigned long long)bits);
      keys[r] = key;
    }
  }
}

// ---------------------------------------------------------------------------
// Per-batch top-4096: 8-pass radix select on u64 keys, gather, then LDS
// bitonic sort by (key desc, idx asc) — exactly lax.top_k's order/tie rule.
// ---------------------------------------------------------------------------
__global__ __launch_bounds__(1024) void k_topk(const unsigned long long* __restrict__ keys,
                                               unsigned int* __restrict__ topk) {
  const int b = blockIdx.x;
  const unsigned long long* K = keys + (size_t)b * NB_V;
  __shared__ unsigned int hist[256];
  __shared__ unsigned long long pfx_s;
  __shared__ int want_s;
  __shared__ unsigned long long skey[TOPK];
  __shared__ unsigned int sidx[TOPK];
  __shared__ int cnt_hi, cnt_eq;
  __shared__ unsigned int eq_idx[1024];
  const int tid = threadIdx.x;
  if (tid == 0) { pfx_s = 0ull; want_s = TOPK; }
  __syncthreads();
  for (int p = 0; p < 8; ++p) {
    const int shift = 56 - 8 * p;
    if (tid < 256) hist[tid] = 0;
    __syncthreads();
    unsigned long long pfx = pfx_s;
    for (int i = tid; i < NB_V; i += 1024) {
      unsigned long long k = K[i];
      bool ok;
      if (p == 0) ok = true;
      else ok = ((k >> (shift + 8)) == (pfx >> (shift + 8)));
      if (ok) atomicAdd(&hist[(unsigned)(k >> shift) & 255u], 1u);
    }
    __syncthreads();
    if (tid == 0) {
      int want = want_s;
      int cum = 0, d = 255;
      for (; d >= 0; --d) {
        int c = (int)hist[d];
        if (cum + c >= want) break;
        cum += c;
      }
      want_s = want - cum;
      pfx_s = pfx_s | ((unsigned long long)d << shift);
    }
    __syncthreads();
  }
  const unsigned long long Kthr = pfx_s;
  const int T = want_s;
  if (tid == 0) { cnt_hi = 0; cnt_eq = 0; }
  __syncthreads();
  for (int i = tid; i < NB_V; i += 1024) {
    unsigned long long k = K[i];
    if (k > Kthr) {
      int pos = atomicAdd(&cnt_hi, 1);
      skey[pos] = k;
      sidx[pos] = (unsigned)i;
    } else if (k == Kthr) {
      int pos = atomicAdd(&cnt_eq, 1);
      if (pos < 1024) eq_idx[pos] = (unsigned)i;
    }
  }
  __syncthreads();
  if (tid == 0) {
    int m = cnt_eq; if (m > 1024) m = 1024;
    for (int a2 = 1; a2 < m; ++a2) {  // insertion sort (m is tiny)
      unsigned v = eq_idx[a2];
      int b2 = a2 - 1;
      while (b2 >= 0 && eq_idx[b2] > v) { eq_idx[b2 + 1] = eq_idx[b2]; --b2; }
      eq_idx[b2 + 1] = v;
    }
    for (int t = 0; t < T; ++t) { skey[cnt_hi + t] = Kthr; sidx[cnt_hi + t] = eq_idx[t]; }
  }
  __syncthreads();
  // bitonic sort: final order = key desc, idx asc
  for (int k2 = 2; k2 <= TOPK; k2 <<= 1) {
    for (int j = k2 >> 1; j > 0; j >>= 1) {
      for (int i = tid; i < TOPK; i += 1024) {
        int ix = i ^ j;
        if (ix > i) {
          unsigned long long ka = skey[i], kb = skey[ix];
          unsigned int ia = sidx[i], ib = sidx[ix];
          bool a_first = (ka > kb) || (ka == kb && ia < ib);
          bool up = (i & k2) == 0;
          if (up ? !a_first : a_first) {
            skey[i] = kb; skey[ix] = ka;
            sidx[i] = ib; sidx[ix] = ia;
          }
        }
      }
      __syncthreads();
    }
  }
  for (int i = tid; i < TOPK; i += 1024) topk[(size_t)b * TOPK + i] = sidx[i];
}

// ---------------------------------------------------------------------------
// D-FPS, latency-optimized: one block per batch, 1024 threads x 4 points.
// All candidate coords live in LDS so every thread reads the winner's coords
// directly -> ONE barrier per iteration (wval double-buffered by parity).
// f64 non-contracted distances; argmax tie -> smallest position.
// ---------------------------------------------------------------------------
__global__ __launch_bounds__(1024) void k_fps(const float* __restrict__ xyz,
                                              const unsigned int* __restrict__ topk,
                                              unsigned int* __restrict__ fpspos) {
  const int b = blockIdx.x;
  const int tid = threadIdx.x;
  __shared__ float cx[TOPK], cy[TOPK], cz[TOPK];
  __shared__ double wval[2][16];
  __shared__ int wpos[2][16];
  float px[4], py[4], pz[4];
  double dist[4];
#pragma unroll
  for (int j = 0; j < 4; ++j) {
    int p = tid + 1024 * j;  // coalesced gather; p ascending in j
    unsigned idx = topk[(size_t)b * TOPK + p];
    size_t base = ((size_t)b * NB_V + idx) * 3;
    float x = xyz[base], y = xyz[base + 1], z = xyz[base + 2];
    px[j] = x; py[j] = y; pz[j] = z;
    cx[p] = x; cy[p] = y; cz[p] = z;
    dist[j] = 1e10;
  }
  if (tid == 0) fpspos[(size_t)b * FPSK] = 0u;
  __syncthreads();
  int wp = 0;  // winner position, known redundantly by every thread
  const int lane = tid & 63, wid = tid >> 6;
  for (int it = 1; it < FPSK; ++it) {
    const int par = it & 1;
    double lx = (double)cx[wp], ly = (double)cy[wp], lz = (double)cz[wp];
    double bv = -1.0;
    int bp = 1 << 30;
#pragma unroll
    for (int j = 0; j < 4; ++j) {
      double dx = (double)px[j] - lx;
      double dy = (double)py[j] - ly;
      double dz = (double)pz[j] - lz;
      double d = __dadd_rn(__dadd_rn(__dmul_rn(dx, dx), __dmul_rn(dy, dy)), __dmul_rn(dz, dz));
      if (d < dist[j]) dist[j] = d;
      if (dist[j] > bv) { bv = dist[j]; bp = tid + 1024 * j; }  // strict >: min p wins
    }
#pragma unroll
    for (int off = 32; off; off >>= 1) {
      double ov = __shfl_xor(bv, off);
      int op = __shfl_xor(bp, off);
      if (ov > bv || (ov == bv && op < bp)) { bv = ov; bp = op; }
    }
    if (lane == 0) { wval[par][wid] = bv; wpos[par][wid] = bp; }
    __syncthreads();
    double mv = wval[par][0];
    int mp = wpos[par][0];
#pragma unroll
    for (int w = 1; w < 16; ++w) {
      double v = wval[par][w];
      int p2 = wpos[par][w];
      if (v > mv || (v == mv && p2 < mp)) { mv = v; mp = p2; }
    }
    wp = mp;
    if (tid == 0) fpspos[(size_t)b * FPSK + it] = (unsigned)wp;
  }
}

// ---------------------------------------------------------------------------
// Final gather: fps_indices (as float), vote_candidates, vote_features.
// ---------------------------------------------------------------------------
__global__ __launch_bounds__(256) void k_gather(const unsigned int* __restrict__ topk,
                                                const unsigned int* __restrict__ fpspos,
                                                const float* __restrict__ feats,
                                                const float* __restrict__ votes_out,
                                                float* __restrict__ o0, float* __restrict__ o1,
                                                float* __restrict__ o5) {
  const int r = blockIdx.x;  // 0 .. B*FPSK-1
  const int b = r / FPSK;
  __shared__ unsigned int gsh;
  if (threadIdx.x == 0) {
    unsigned pos = fpspos[r];
    unsigned local = topk[(size_t)b * TOPK + pos];
    gsh = (unsigned)(b * NB_V) + local;
  }
  __syncthreads();
  const unsigned g = gsh;
  o1[(size_t)r * 256 + threadIdx.x] = feats[(size_t)g * 256 + threadIdx.x];
  if (threadIdx.x < 4) o0[(size_t)r * 4 + threadIdx.x] = votes_out[(size_t)g * 4 + threadIdx.x];
  if (threadIdx.x == 4) o5[r] = (float)g;
}

// ---------------------------------------------------------------------------
extern "C" void kernel_launch(void* const* d_in, const int* in_sizes, int n_in,
                              void* d_out, int out_size, void* d_ws, size_t ws_size,
                              hipStream_t stream) {
  const float* xyz = (const float*)d_in[0];
  const float* feats = (const float*)d_in[1];
  const float* w_off1 = (const float*)d_in[2];
  const float* g_off1 = (const float*)d_in[3];
  const float* be_off1 = (const float*)d_in[4];
  const float* w_off2 = (const float*)d_in[5];
  const float* b_off2 = (const float*)d_in[6];
  const float* w_cls1 = (const float*)d_in[7];
  const float* g_cls1 = (const float*)d_in[8];
  const float* be_cls1 = (const float*)d_in[9];
  const float* w_cls2 = (const float*)d_in[10];
  const float* b_cls2 = (const float*)d_in[11];

  const int N = in_sizes[0] / 3;
  const int B = N / NB_V;
  const int BP = B * FPSK;

  float* out = (float*)d_out;
  float* o0 = out;                           // vote_candidates (BP,4)
  float* o1 = o0 + (size_t)BP * 4;           // vote_features   (BP,256)
  float* o2 = o1 + (size_t)BP * 256;         // seeds           (N,4)
  float* o3 = o2 + (size_t)N * 4;            // seed_cls        (N,3)
  float* o4 = o3 + (size_t)N * 3;            // votes           (N,4)
  float* o5 = o4 + (size_t)N * 4;            // fps_indices     (BP,)

  char* w = (char*)d_ws;
  float* Hoff = (float*)w;                                       // N*256*4
  float* Hcls = (float*)(w + (size_t)N * 1024);                  // N*256*4
  double* part = (double*)(w + (size_t)N * 2048);                // 1024*512*2*8
  double* aarr = (double*)(w + (size_t)N * 2048 + 8388608);      // 512*8
  double* carr = aarr + 512;                                     // 512*8
  unsigned long long* keys =
      (unsigned long long*)(w + (size_t)N * 2048 + 8388608 + 8192);       // N*8
  unsigned int* topkbuf = (unsigned int*)((char*)keys + (size_t)N * 8);   // B*4096*4
  unsigned int* fpspos = topkbuf + (size_t)B * TOPK;                      // B*2048*4

  k_gemm<float><<<dim3((N / 64) * 4), dim3(256), 0, stream>>>(feats, w_off1, Hoff, N);
  k_gemm<double><<<dim3((N / 64) * 4), dim3(256), 0, stream>>>(feats, w_cls1, Hcls, N);
  k_stats<<<dim3(1024), dim3(256), 0, stream>>>(Hoff, Hcls, part, N);
  k_statsfin<<<dim3(1), dim3(512), 0, stream>>>(part, g_off1, be_off1, g_cls1, be_cls1,
                                                aarr, carr, 1024, N);
  k_fuse<<<dim3(1024), dim3(256), 0, stream>>>(Hoff, Hcls, xyz, w_off2, b_off2, w_cls2,
                                               b_cls2, aarr, carr, o2, o3, o4, keys, N);
  k_topk<<<dim3(B), dim3(1024), 0, stream>>>(keys, topkbuf);
  k_fps<<<dim3(B), dim3(1024), 0, stream>>>(xyz, topkbuf, fpspos);
  k_gather<<<dim3(BP), dim3(256), 0, stream>>>(topkbuf, fpspos, feats, o4, o0, o1, o5);
}

// Round 3
// 5229.873 us; speedup vs baseline: 1.4291x; 1.3940x over previous
//
#include <hip/hip_runtime.h>

#define NB_V 65536
#define TOPK 4096
#define FPSK 2048

// ---------------------------------------------------------------------------
// GEMM: H(N,256) = A(N,256) @ W(256,256), accumulator precision templated.
// ACC=double for the cls branch (discrete top-k selection downstream needs
// near-exact scores); ACC=float for the offset branch (2% tolerance).
// ---------------------------------------------------------------------------
template <typename ACC>
__global__ __launch_bounds__(256) void k_gemm(const float* __restrict__ A,
                                              const float* __restrict__ W,
                                              float* __restrict__ H, int N) {
  __shared__ float As[64][36];  // 64 rows x 32 k, padded
  __shared__ float Bs[32][68];  // 32 k x 64 cols, padded
  const int tid = threadIdx.x;
  const int tx = tid & 15, ty = tid >> 4;
  const int cb = blockIdx.x & 3;
  const int rb = blockIdx.x >> 2;
  ACC acc[4][4];
#pragma unroll
  for (int i = 0; i < 4; ++i)
#pragma unroll
    for (int j = 0; j < 4; ++j) acc[i][j] = (ACC)0;

  for (int kc = 0; kc < 256; kc += 32) {
#pragma unroll
    for (int l = 0; l < 2; ++l) {
      int f = tid + 256 * l;
      int r = f >> 3, qc = (f & 7) * 4;
      float4 v = *reinterpret_cast<const float4*>(&A[(size_t)(rb * 64 + r) * 256 + kc + qc]);
      *reinterpret_cast<float4*>(&As[r][qc]) = v;
    }
#pragma unroll
    for (int l = 0; l < 2; ++l) {
      int f = tid + 256 * l;
      int kr = f >> 4, qc = (f & 15) * 4;
      float4 v = *reinterpret_cast<const float4*>(&W[(size_t)(kc + kr) * 256 + cb * 64 + qc]);
      *reinterpret_cast<float4*>(&Bs[kr][qc]) = v;
    }
    __syncthreads();
#pragma unroll 4
    for (int kk = 0; kk < 32; ++kk) {
      float a0[4], b0[4];
#pragma unroll
      for (int i = 0; i < 4; ++i) a0[i] = As[ty + 16 * i][kk];
#pragma unroll
      for (int j = 0; j < 4; ++j) b0[j] = Bs[kk][tx + 16 * j];
#pragma unroll
      for (int i = 0; i < 4; ++i)
#pragma unroll
        for (int j = 0; j < 4; ++j) acc[i][j] += (ACC)a0[i] * (ACC)b0[j];
    }
    __syncthreads();
  }
#pragma unroll
  for (int i = 0; i < 4; ++i)
#pragma unroll
    for (int j = 0; j < 4; ++j)
      H[(size_t)(rb * 64 + ty + 16 * i) * 256 + cb * 64 + tx + 16 * j] = (float)acc[i][j];
}

// ---------------------------------------------------------------------------
// Column mean/meansq partials (f64, deterministic fixed reduction tree).
// ---------------------------------------------------------------------------
__global__ __launch_bounds__(256) void k_stats(const float* __restrict__ Hoff,
                                               const float* __restrict__ Hcls,
                                               double* __restrict__ part, int N) {
  const int rpb = N / 1024;
  const int r0 = blockIdx.x * rpb;
  const int t = threadIdx.x;
  double s0 = 0, q0 = 0, s1 = 0, q1 = 0;
  for (int r = r0; r < r0 + rpb; ++r) {
    double v = (double)Hoff[(size_t)r * 256 + t];
    s0 += v; q0 = fma(v, v, q0);
    double w = (double)Hcls[(size_t)r * 256 + t];
    s1 += w; q1 = fma(w, w, q1);
  }
  double* o = part + ((size_t)blockIdx.x * 512 + t) * 2;
  o[0] = s0; o[1] = q0;
  o = part + ((size_t)blockIdx.x * 512 + 256 + t) * 2;
  o[0] = s1; o[1] = q1;
}

__global__ void k_statsfin(const double* __restrict__ part,
                           const float* __restrict__ g_off, const float* __restrict__ be_off,
                           const float* __restrict__ g_cls, const float* __restrict__ be_cls,
                           double* __restrict__ aarr, double* __restrict__ carr,
                           int nparts, int N) {
  const int c = threadIdx.x;  // 512 threads
  double s = 0, q = 0;
  for (int p = 0; p < nparts; ++p) {
    s += part[((size_t)p * 512 + c) * 2];
    q += part[((size_t)p * 512 + c) * 2 + 1];
  }
  double mean = s / (double)N;
  double var = q / (double)N - mean * mean;
  double g = (c < 256) ? (double)g_off[c] : (double)g_cls[c - 256];
  double be = (c < 256) ? (double)be_off[c] : (double)be_cls[c - 256];
  double a = g / sqrt(var + 1e-5);
  aarr[c] = a;
  carr[c] = be - mean * a;  // val = h*a + c  ==  (h-mean)*rsqrt*gamma + beta
}

// ---------------------------------------------------------------------------
// Fused BN+ReLU+layer2 for both branches; writes seeds, seed_cls, votes, and
// the f64-score sort key. One wave per row; lane l handles cols {l+64q}.
// ---------------------------------------------------------------------------
__global__ __launch_bounds__(256) void k_fuse(const float* __restrict__ Hoff,
                                              const float* __restrict__ Hcls,
                                              const float* __restrict__ xyz,
                                              const float* __restrict__ w_off2,
                                              const float* __restrict__ b_off2,
                                              const float* __restrict__ w_cls2,
                                              const float* __restrict__ b_cls2,
                                              const double* __restrict__ aarr,
                                              const double* __restrict__ carr,
                                              float* __restrict__ out_seeds,
                                              float* __restrict__ out_cls,
                                              float* __restrict__ out_votes,
                                              unsigned long long* __restrict__ keys,
                                              int N) {
  __shared__ double sa[512], sc[512];
  __shared__ double w2[512][3];
  const int tid = threadIdx.x;
  for (int i = tid; i < 512; i += 256) {
    sa[i] = aarr[i];
    sc[i] = carr[i];
#pragma unroll
    for (int k = 0; k < 3; ++k)
      w2[i][k] = (i < 256) ? (double)w_off2[i * 3 + k] : (double)w_cls2[(i - 256) * 3 + k];
  }
  __syncthreads();
  const int lane = tid & 63, wid = tid >> 6;
  const int gw = blockIdx.x * 4 + wid;  // 4096 waves total
  for (int r = gw; r < N; r += 4096) {
    double po0 = 0, po1 = 0, po2 = 0, pc0 = 0, pc1 = 0, pc2 = 0;
#pragma unroll
    for (int q = 0; q < 4; ++q) {
      int c = lane + 64 * q;
      double h = (double)Hoff[(size_t)r * 256 + c];
      double v = fma(h, sa[c], sc[c]);
      v = v > 0.0 ? v : 0.0;
      po0 = fma(v, w2[c][0], po0);
      po1 = fma(v, w2[c][1], po1);
      po2 = fma(v, w2[c][2], po2);
      int c2 = 256 + c;
      double h2 = (double)Hcls[(size_t)r * 256 + c];
      double v2 = fma(h2, sa[c2], sc[c2]);
      v2 = v2 > 0.0 ? v2 : 0.0;
      pc0 = fma(v2, w2[c2][0], pc0);
      pc1 = fma(v2, w2[c2][1], pc1);
      pc2 = fma(v2, w2[c2][2], pc2);
    }
#pragma unroll
    for (int off = 32; off; off >>= 1) {
      po0 += __shfl_xor(po0, off); po1 += __shfl_xor(po1, off); po2 += __shfl_xor(po2, off);
      pc0 += __shfl_xor(pc0, off); pc1 += __shfl_xor(pc1, off); pc2 += __shfl_xor(pc2, off);
    }
    if (lane == 0) {
      float x = xyz[(size_t)r * 3], y = xyz[(size_t)r * 3 + 1], z = xyz[(size_t)r * 3 + 2];
      float bs = (float)(r >> 16);
      out_seeds[(size_t)r * 4 + 0] = bs;
      out_seeds[(size_t)r * 4 + 1] = x;
      out_seeds[(size_t)r * 4 + 2] = y;
      out_seeds[(size_t)r * 4 + 3] = z;
      double offv[3] = {po0 + (double)b_off2[0], po1 + (double)b_off2[1], po2 + (double)b_off2[2]};
      const double rng[3] = {3.0, 3.0, 2.0};
      float pxyz[3] = {x, y, z};
      out_votes[(size_t)r * 4 + 0] = bs;
#pragma unroll
      for (int k = 0; k < 3; ++k) {
        double lim = offv[k];
        lim = lim < -rng[k] ? -rng[k] : lim;
        lim = lim > rng[k] ? rng[k] : lim;
        out_votes[(size_t)r * 4 + 1 + k] = (float)((double)pxyz[k] + lim);
      }
      double c0 = pc0 + (double)b_cls2[0];
      double c1 = pc1 + (double)b_cls2[1];
      double c2v = pc2 + (double)b_cls2[2];
      out_cls[(size_t)r * 3 + 0] = (float)c0;
      out_cls[(size_t)r * 3 + 1] = (float)c1;
      out_cls[(size_t)r * 3 + 2] = (float)c2v;
      double s = c0 > c1 ? c0 : c1;
      s = s > c2v ? s : c2v;
      long long bits = __double_as_longlong(s);
      unsigned long long key =
          bits >= 0 ? ((unsigned long long)bits | 0x8000000000000000ull) : ~((unsigned long long)bits);
      keys[r] = key;
    }
  }
}

// ---------------------------------------------------------------------------
// Per-batch top-4096: 8-pass radix select on u64 keys, gather, then LDS
// bitonic sort by (key desc, idx asc) — exactly lax.top_k's order/tie rule.
// ---------------------------------------------------------------------------
__global__ __launch_bounds__(1024) void k_topk(const unsigned long long* __restrict__ keys,
                                               unsigned int* __restrict__ topk) {
  const int b = blockIdx.x;
  const unsigned long long* K = keys + (size_t)b * NB_V;
  __shared__ unsigned int hist[256];
  __shared__ unsigned long long pfx_s;
  __shared__ int want_s;
  __shared__ unsigned long long skey[TOPK];
  __shared__ unsigned int sidx[TOPK];
  __shared__ int cnt_hi, cnt_eq;
  __shared__ unsigned int eq_idx[1024];
  const int tid = threadIdx.x;
  if (tid == 0) { pfx_s = 0ull; want_s = TOPK; }
  __syncthreads();
  for (int p = 0; p < 8; ++p) {
    const int shift = 56 - 8 * p;
    if (tid < 256) hist[tid] = 0;
    __syncthreads();
    unsigned long long pfx = pfx_s;
    for (int i = tid; i < NB_V; i += 1024) {
      unsigned long long k = K[i];
      bool ok;
      if (p == 0) ok = true;
      else ok = ((k >> (shift + 8)) == (pfx >> (shift + 8)));
      if (ok) atomicAdd(&hist[(unsigned)(k >> shift) & 255u], 1u);
    }
    __syncthreads();
    if (tid == 0) {
      int want = want_s;
      int cum = 0, d = 255;
      for (; d >= 0; --d) {
        int c = (int)hist[d];
        if (cum + c >= want) break;
        cum += c;
      }
      want_s = want - cum;
      pfx_s = pfx_s | ((unsigned long long)d << shift);
    }
    __syncthreads();
  }
  const unsigned long long Kthr = pfx_s;
  const int T = want_s;
  if (tid == 0) { cnt_hi = 0; cnt_eq = 0; }
  __syncthreads();
  for (int i = tid; i < NB_V; i += 1024) {
    unsigned long long k = K[i];
    if (k > Kthr) {
      int pos = atomicAdd(&cnt_hi, 1);
      skey[pos] = k;
      sidx[pos] = (unsigned)i;
    } else if (k == Kthr) {
      int pos = atomicAdd(&cnt_eq, 1);
      if (pos < 1024) eq_idx[pos] = (unsigned)i;
    }
  }
  __syncthreads();
  if (tid == 0) {
    int m = cnt_eq; if (m > 1024) m = 1024;
    for (int a2 = 1; a2 < m; ++a2) {  // insertion sort (m is tiny)
      unsigned v = eq_idx[a2];
      int b2 = a2 - 1;
      while (b2 >= 0 && eq_idx[b2] > v) { eq_idx[b2 + 1] = eq_idx[b2]; --b2; }
      eq_idx[b2 + 1] = v;
    }
    for (int t = 0; t < T; ++t) { skey[cnt_hi + t] = Kthr; sidx[cnt_hi + t] = eq_idx[t]; }
  }
  __syncthreads();
  // bitonic sort: final order = key desc, idx asc
  for (int k2 = 2; k2 <= TOPK; k2 <<= 1) {
    for (int j = k2 >> 1; j > 0; j >>= 1) {
      for (int i = tid; i < TOPK; i += 1024) {
        int ix = i ^ j;
        if (ix > i) {
          unsigned long long ka = skey[i], kb = skey[ix];
          unsigned int ia = sidx[i], ib = sidx[ix];
          bool a_first = (ka > kb) || (ka == kb && ia < ib);
          bool up = (i & k2) == 0;
          if (up ? !a_first : a_first) {
            skey[i] = kb; skey[ix] = ka;
            sidx[i] = ib; sidx[ix] = ia;
          }
        }
      }
      __syncthreads();
    }
  }
  for (int i = tid; i < TOPK; i += 1024) topk[(size_t)b * TOPK + i] = sidx[i];
}

// ---------------------------------------------------------------------------
// D-FPS, LDS-traffic-optimized: one block per batch, 256 threads x 16 points
// in f64 registers. Coords in LDS as float4 (1 ds_read_b128 broadcast for
// the winner); wave winners packed as ulonglong2 (1 write + 4 reads).
// One barrier per iteration (parity double-buffer). f64 non-contracted
// distances; argmax tie -> smallest position (np.argmax first-occurrence).
// ---------------------------------------------------------------------------
__global__ __launch_bounds__(256, 1) void k_fps(const float* __restrict__ xyz,
                                                const unsigned int* __restrict__ topk,
                                                unsigned int* __restrict__ fpspos) {
  const int b = blockIdx.x;
  const int tid = threadIdx.x;
  __shared__ float4 cpos[TOPK];           // 64 KB
  __shared__ ulonglong2 wred[2][4];       // (valbits, pos) per wave, by parity
  double px[16], py[16], pz[16], dist[16];
#pragma unroll
  for (int j = 0; j < 16; ++j) {
    int p = tid + 256 * j;  // coalesced; p ascending in j for fixed tid
    unsigned idx = topk[(size_t)b * TOPK + p];
    size_t base = ((size_t)b * NB_V + idx) * 3;
    float x = xyz[base], y = xyz[base + 1], z = xyz[base + 2];
    px[j] = (double)x; py[j] = (double)y; pz[j] = (double)z;
    cpos[p] = make_float4(x, y, z, 0.0f);
    dist[j] = 1e10;
  }
  if (tid == 0) fpspos[(size_t)b * FPSK] = 0u;
  __syncthreads();
  int wp = 0;  // winner position, known redundantly by every thread
  const int lane = tid & 63, wid = tid >> 6;
  for (int it = 1; it < FPSK; ++it) {
    const int par = it & 1;
    float4 cp = cpos[wp];  // one ds_read_b128, broadcast
    double lx = (double)cp.x, ly = (double)cp.y, lz = (double)cp.z;
    double bv = -1.0;
    int bp = 1 << 30;
#pragma unroll
    for (int j = 0; j < 16; ++j) {
      double dx = px[j] - lx;
      double dy = py[j] - ly;
      double dz = pz[j] - lz;
      double d = __dadd_rn(__dadd_rn(__dmul_rn(dx, dx), __dmul_rn(dy, dy)), __dmul_rn(dz, dz));
      if (d < dist[j]) dist[j] = d;
      if (dist[j] > bv) { bv = dist[j]; bp = tid + 256 * j; }  // strict >: min p wins
    }
#pragma unroll
    for (int off = 32; off; off >>= 1) {
      double ov = __shfl_xor(bv, off);
      int op = __shfl_xor(bp, off);
      if (ov > bv || (ov == bv && op < bp)) { bv = ov; bp = op; }
    }
    if (lane == 0)
      wred[par][wid] = make_ulonglong2((unsigned long long)__double_as_longlong(bv),
                                       (unsigned long long)bp);
    __syncthreads();
    double mv = -2.0;
    int mp = 1 << 30;
#pragma unroll
    for (int w = 0; w < 4; ++w) {
      ulonglong2 e = wred[par][w];  // ds_read_b128 broadcast
      double v = __longlong_as_double((long long)e.x);
      int p2 = (int)e.y;
      if (v > mv || (v == mv && p2 < mp)) { mv = v; mp = p2; }
    }
    wp = mp;
    if (tid == 0) fpspos[(size_t)b * FPSK + it] = (unsigned)wp;
  }
}

// ---------------------------------------------------------------------------
// Final gather: fps_indices (as float), vote_candidates, vote_features.
// ---------------------------------------------------------------------------
__global__ __launch_bounds__(256) void k_gather(const unsigned int* __restrict__ topk,
                                                const unsigned int* __restrict__ fpspos,
                                                const float* __restrict__ feats,
                                                const float* __restrict__ votes_out,
                                                float* __restrict__ o0, float* __restrict__ o1,
                                                float* __restrict__ o5) {
  const int r = blockIdx.x;  // 0 .. B*FPSK-1
  const int b = r / FPSK;
  __shared__ unsigned int gsh;
  if (threadIdx.x == 0) {
    unsigned pos = fpspos[r];
    unsigned local = topk[(size_t)b * TOPK + pos];
    gsh = (unsigned)(b * NB_V) + local;
  }
  __syncthreads();
  const unsigned g = gsh;
  o1[(size_t)r * 256 + threadIdx.x] = feats[(size_t)g * 256 + threadIdx.x];
  if (threadIdx.x < 4) o0[(size_t)r * 4 + threadIdx.x] = votes_out[(size_t)g * 4 + threadIdx.x];
  if (threadIdx.x == 4) o5[r] = (float)g;
}

// ---------------------------------------------------------------------------
extern "C" void kernel_launch(void* const* d_in, const int* in_sizes, int n_in,
                              void* d_out, int out_size, void* d_ws, size_t ws_size,
                              hipStream_t stream) {
  const float* xyz = (const float*)d_in[0];
  const float* feats = (const float*)d_in[1];
  const float* w_off1 = (const float*)d_in[2];
  const float* g_off1 = (const float*)d_in[3];
  const float* be_off1 = (const float*)d_in[4];
  const float* w_off2 = (const float*)d_in[5];
  const float* b_off2 = (const float*)d_in[6];
  const float* w_cls1 = (const float*)d_in[7];
  const float* g_cls1 = (const float*)d_in[8];
  const float* be_cls1 = (const float*)d_in[9];
  const float* w_cls2 = (const float*)d_in[10];
  const float* b_cls2 = (const float*)d_in[11];

  const int N = in_sizes[0] / 3;
  const int B = N / NB_V;
  const int BP = B * FPSK;

  float* out = (float*)d_out;
  float* o0 = out;                           // vote_candidates (BP,4)
  float* o1 = o0 + (size_t)BP * 4;           // vote_features   (BP,256)
  float* o2 = o1 + (size_t)BP * 256;         // seeds           (N,4)
  float* o3 = o2 + (size_t)N * 4;            // seed_cls        (N,3)
  float* o4 = o3 + (size_t)N * 3;            // votes           (N,4)
  float* o5 = o4 + (size_t)N * 4;            // fps_indices     (BP,)

  char* w = (char*)d_ws;
  float* Hoff = (float*)w;                                       // N*256*4
  float* Hcls = (float*)(w + (size_t)N * 1024);                  // N*256*4
  double* part = (double*)(w + (size_t)N * 2048);                // 1024*512*2*8
  double* aarr = (double*)(w + (size_t)N * 2048 + 8388608);      // 512*8
  double* carr = aarr + 512;                                     // 512*8
  unsigned long long* keys =
      (unsigned long long*)(w + (size_t)N * 2048 + 8388608 + 8192);       // N*8
  unsigned int* topkbuf = (unsigned int*)((char*)keys + (size_t)N * 8);   // B*4096*4
  unsigned int* fpspos = topkbuf + (size_t)B * TOPK;                      // B*2048*4

  k_gemm<float><<<dim3((N / 64) * 4), dim3(256), 0, stream>>>(feats, w_off1, Hoff, N);
  k_gemm<double><<<dim3((N / 64) * 4), dim3(256), 0, stream>>>(feats, w_cls1, Hcls, N);
  k_stats<<<dim3(1024), dim3(256), 0, stream>>>(Hoff, Hcls, part, N);
  k_statsfin<<<dim3(1), dim3(512), 0, stream>>>(part, g_off1, be_off1, g_cls1, be_cls1,
                                                aarr, carr, 1024, N);
  k_fuse<<<dim3(1024), dim3(256), 0, stream>>>(Hoff, Hcls, xyz, w_off2, b_off2, w_cls2,
                                               b_cls2, aarr, carr, o2, o3, o4, keys, N);
  k_topk<<<dim3(B), dim3(1024), 0, stream>>>(keys, topkbuf);
  k_fps<<<dim3(B), dim3(256), 0, stream>>>(xyz, topkbuf, fpspos);
  k_gather<<<dim3(BP), dim3(256), 0, stream>>>(topkbuf, fpspos, feats, o4, o0, o1, o5);
}